// Round 13
// baseline (318.342 us; speedup 1.0000x reference)
//
#include <hip/hip_runtime.h>
#include <hip/hip_bf16.h>

#define N_NODES 8192
#define D_FEAT 128

typedef __bf16 bf16x8 __attribute__((ext_vector_type(8)));
typedef float f32x4 __attribute__((ext_vector_type(4)));

// Barrier that waits ONLY on LDS ops (lgkmcnt(0)) — does NOT drain vmcnt,
// so global stores/loads issued before it stay in flight across the barrier.
// Inline asm with "memory" clobber = real compiler fence (R8-verified).
__device__ __forceinline__ void lgkm_barrier() {
  asm volatile("s_waitcnt lgkmcnt(0)\n\ts_barrier" ::: "memory");
}
// Wave-local LDS write->read ordering point (no cross-wave barrier needed).
__device__ __forceinline__ void lgkm_fence() {
  asm volatile("s_waitcnt lgkmcnt(0)" ::: "memory");
}

// ---- cold path: on-the-fly LSH band-collision check (never taken for the
// given Gaussian inputs: max off-diag cosine ~0.49 << 0.75).
__device__ __attribute__((noinline)) bool lsh_collide(
    const float* __restrict__ z, const float* __restrict__ H, int i, int j) {
  for (int b = 0; b < 64; ++b) {          // 64 bands x 8 bits
    unsigned ci = 0, cj = 0;
    for (int bit = 0; bit < 8; ++bit) {
      int col = b * 8 + bit;
      float di = 0.f, dj = 0.f;
      for (int k = 0; k < D_FEAT; ++k) {
        float h = H[(size_t)k * 512 + col];
        di += z[(size_t)i * D_FEAT + k] * h;
        dj += z[(size_t)j * D_FEAT + k] * h;
      }
      if (di > 0.f) ci |= (1u << bit);
      if (dj > 0.f) cj |= (1u << bit);
    }
    if (ci == cj) return true;
  }
  return false;
}

__device__ __forceinline__ unsigned pack_bf16x2(float x, float y) {
  __hip_bfloat16 bx = __float2bfloat16(x), by = __float2bfloat16(y);
  return (unsigned)(*(unsigned short*)&bx) |
         ((unsigned)(*(unsigned short*)&by) << 16);
}

// Issue the 16 dwordx4 loads for this thread's share of a 128-row z tile.
__device__ __forceinline__ void load_rows(const float* __restrict__ z, int blk,
                                          int tid, float4 (&v)[16]) {
  int row = tid >> 1, half = tid & 1;
  const float4* src = (const float4*)(z + (size_t)(blk * 128 + row) * D_FEAT + half * 64);
#pragma unroll
  for (int c = 0; c < 16; ++c) v[c] = src[c];
}

// Consume prefetched rows: pair-shuffle norm reduce, bf16 pack, XOR-swizzled
// ds_write (layout identical to R8-verified stage_tile).
__device__ __forceinline__ void reduce_store(unsigned short (*T)[128], int tid,
                                             const float4 (&v)[16]) {
  int row = tid >> 1, half = tid & 1;
  float ss = 0.f;
#pragma unroll
  for (int c = 0; c < 16; ++c)
    ss += v[c].x * v[c].x + v[c].y * v[c].y + v[c].z * v[c].z + v[c].w * v[c].w;
  ss += __shfl_xor(ss, 1);
  float inv = rsqrtf(ss);
#pragma unroll
  for (int c = 0; c < 8; ++c) {
    float4 a = v[2 * c], b = v[2 * c + 1];
    uint4 o;
    o.x = pack_bf16x2(a.x * inv, a.y * inv);
    o.y = pack_bf16x2(a.z * inv, a.w * inv);
    o.z = pack_bf16x2(b.x * inv, b.y * inv);
    o.w = pack_bf16x2(b.z * inv, b.w * inv);
    ((uint4*)&T[row][0])[(half * 8 + c) ^ (row & 15)] = o;
  }
}

// Persistent-block fused kernel (R8 structure + R13 prefetch placement).
// Block b: bn resident (Bs staged once), 8 bm-rounds. The A-tile z loads
// for round t+1 are issued AFTER round t's MFMA (fa/fb dead, acc dying
// through the epilogue — no VGPR spill, unlike R12) but BEFORE round t's
// slab stores enter the per-wave in-order vmcnt FIFO. So the staging wait
// at t+1 is vmcnt(16): it drains only the loads; the 16 stores stay in
// flight through round t+1's MFMA — the store drain leaves the critical
// path and rounds become write-throughput-limited.
__global__ __launch_bounds__(256, 2) void sim_kernel(const float* __restrict__ z,
                                                     const float* __restrict__ H,
                                                     float* __restrict__ out) {
  __shared__ __align__(16) unsigned char smem_raw[65536];
  unsigned short (*As)[128] = (unsigned short (*)[128])smem_raw;            // 32 KB (aliased by fS slabs)
  unsigned short (*Bs)[128] = (unsigned short (*)[128])(smem_raw + 32768);  // 32 KB persistent
  float* fS = (float*)smem_raw;   // per-wave slabs: wv*2048 + parity*1024 floats

  int tid = threadIdx.x;
  int b = (int)blockIdx.x;
  int bm0 = b & 7;                // XCD id under round-robin dispatch (R11)
  int bn = b >> 3;                // 0..63

  int wv = tid >> 6, lane = tid & 63;
  int wm = (wv >> 1) * 64, wn = (wv & 1) * 64;
  int m16 = lane & 15, g = lane >> 4;
  float* fSw = fS + wv * 2048;

  // ---- stage Bs once (resident for all 8 rounds) ----
  {
    float4 bv[16];
    load_rows(z, bn, tid, bv);
    reduce_store(Bs, tid, bv);
  }
  // prefetch round 0's A rows
  float4 pv[16];
  load_rows(z, bm0 * 8, tid, pv);

  for (int t = 0; t < 8; ++t) {
    int bm = bm0 * 8 + t;

    // All waves' slab ds_reads from round t-1 done -> As region writable.
    // Stores from round t-1 remain in flight (lgkm-only barrier).
    lgkm_barrier();
    reduce_store(As, tid, pv);   // waits only on loads(t): OLDER than
                                 // stores(t-1) in the vmcnt FIFO
    lgkm_barrier();              // staging visible to all waves

    // ---- MFMA: wave -> 64x64 quadrant, 4x4 tiles of 16x16x32, K=128 ----
    f32x4 acc[4][4] = {};
#pragma unroll
    for (int kc = 0; kc < 4; ++kc) {
      bf16x8 fa[4], fb[4];
      int chunk = kc * 4 + g;
      int cs = (chunk ^ m16) * 8;   // row bases multiples of 16 -> row&15 == m16
#pragma unroll
      for (int tt = 0; tt < 4; ++tt) {
        fa[tt] = *(const bf16x8*)&As[wm + tt * 16 + m16][cs];
        fb[tt] = *(const bf16x8*)&Bs[wn + tt * 16 + m16][cs];
      }
#pragma unroll
      for (int tm = 0; tm < 4; ++tm)
#pragma unroll
        for (int tn = 0; tn < 4; ++tn)
          acc[tm][tn] = __builtin_amdgcn_mfma_f32_16x16x32_bf16(fa[tm], fb[tn], acc[tm][tn], 0, 0, 0);
    }

    // R13: prefetch NEXT round's A rows here — after MFMA (fa/fb dead, no
    // spill) and BEFORE this round's slab stores are issued (loads older
    // than stores in the FIFO).
    if (t < 7) load_rows(z, bm0 * 8 + t + 1, tid, pv);

    lgkm_barrier();   // all waves' As frag reads done before slab writes

    // ---- epilogue + wave-local slab stores (R8-verified) ----
    // C/D layout: col=lane&15, row=g*4+r. Slab = 16 rows x 64 cols fp32,
    // swizzle chunk' = (col>>2) ^ rowInSlab.
#pragma unroll
    for (int tm = 0; tm < 4; ++tm) {
      float* slab = fSw + (tm & 1) * 1024;
#pragma unroll
      for (int tn = 0; tn < 4; ++tn) {
        int colq = tn * 16 + m16;          // quadrant-local col 0..63
        int j = bn * 128 + wn + colq;
        f32x4 c = acc[tm][tn];
#pragma unroll
        for (int r = 0; r < 4; ++r) {
          int rs = g * 4 + r;              // slab row 0..15
          int i = bm * 128 + wm + tm * 16 + rs;
          float s = c[r];
          float val = 0.0f;
          if (i == j) {
            val = 1.0f;
          } else if (s > 0.75f) {
            if (lsh_collide(z, H, i, j)) val = s;   // cold path
          }
          slab[rs * 64 + (((colq >> 2) ^ rs) << 2) + (colq & 3)] = val;
        }
      }
      lgkm_fence();   // slab writes complete before cross-lane readback
      // store slab: 4 instrs, each 4 rows x 256B contiguous segments
#pragma unroll
      for (int it = 0; it < 4; ++it) {
        int rs = it * 4 + g;
        f32x4 v = *(const f32x4*)&slab[rs * 64 + ((m16 ^ rs) << 2)];
        int grow = bm * 128 + wm + tm * 16 + rs;
        *(f32x4*)&out[(size_t)grow * N_NODES + bn * 128 + wn + m16 * 4] = v;
      }
    }
  }
}

extern "C" void kernel_launch(void* const* d_in, const int* in_sizes, int n_in,
                              void* d_out, int out_size, void* d_ws, size_t ws_size,
                              hipStream_t stream) {
  const float* z = (const float*)d_in[0];   // [8192, 128] fp32
  const float* H = (const float*)d_in[1];   // [128, 512] fp32
  // d_in[2] = edge_index, unused by the reference forward.
  float* out = (float*)d_out;               // [8192, 8192] fp32
  (void)d_ws; (void)ws_size;

  sim_kernel<<<512, 256, 0, stream>>>(z, H, out);
}

// Round 14
// 277.109 us; speedup vs baseline: 1.1488x; 1.1488x over previous
//
#include <hip/hip_runtime.h>
#include <hip/hip_bf16.h>

#define N_NODES 8192
#define D_FEAT 128

typedef __bf16 bf16x8 __attribute__((ext_vector_type(8)));
typedef float f32x4 __attribute__((ext_vector_type(4)));

// Barrier that waits ONLY on LDS ops (lgkmcnt(0)) — does NOT drain vmcnt,
// so global stores issued before it stay in flight across the barrier.
// Inline asm with "memory" clobber = real compiler fence (R8-verified, -22us;
// R7's builtin version was NOT a compiler fence and miscompiled).
__device__ __forceinline__ void lgkm_barrier() {
  asm volatile("s_waitcnt lgkmcnt(0)\n\ts_barrier" ::: "memory");
}
// Wave-local LDS write->read ordering point (no cross-wave barrier needed).
__device__ __forceinline__ void lgkm_fence() {
  asm volatile("s_waitcnt lgkmcnt(0)" ::: "memory");
}

// ---- cold path: on-the-fly LSH band-collision check (never taken for the
// given Gaussian inputs: max off-diag cosine ~0.49 << 0.75).
__device__ __attribute__((noinline)) bool lsh_collide(
    const float* __restrict__ z, const float* __restrict__ H, int i, int j) {
  for (int b = 0; b < 64; ++b) {          // 64 bands x 8 bits
    unsigned ci = 0, cj = 0;
    for (int bit = 0; bit < 8; ++bit) {
      int col = b * 8 + bit;
      float di = 0.f, dj = 0.f;
      for (int k = 0; k < D_FEAT; ++k) {
        float h = H[(size_t)k * 512 + col];
        di += z[(size_t)i * D_FEAT + k] * h;
        dj += z[(size_t)j * D_FEAT + k] * h;
      }
      if (di > 0.f) ci |= (1u << bit);
      if (dj > 0.f) cj |= (1u << bit);
    }
    if (ci == cj) return true;
  }
  return false;
}

__device__ __forceinline__ unsigned pack_bf16x2(float x, float y) {
  __hip_bfloat16 bx = __float2bfloat16(x), by = __float2bfloat16(y);
  return (unsigned)(*(unsigned short*)&bx) |
         ((unsigned)(*(unsigned short*)&by) << 16);
}

// Normalize 128 z-rows of block `blk` into bf16 tile T (XOR-swizzled 16B
// chunks). 2 threads/row, pair-shuffle reduce. (R4/R8-verified.)
__device__ __forceinline__ void stage_tile(const float* __restrict__ z, int blk,
                                           unsigned short (*T)[128], int tid) {
  int row = tid >> 1, half = tid & 1;
  const float4* src = (const float4*)(z + (size_t)(blk * 128 + row) * D_FEAT + half * 64);
  float4 v[16];
#pragma unroll
  for (int c = 0; c < 16; ++c) v[c] = src[c];
  float ss = 0.f;
#pragma unroll
  for (int c = 0; c < 16; ++c)
    ss += v[c].x * v[c].x + v[c].y * v[c].y + v[c].z * v[c].z + v[c].w * v[c].w;
  ss += __shfl_xor(ss, 1);
  float inv = rsqrtf(ss);
#pragma unroll
  for (int c = 0; c < 8; ++c) {
    float4 a = v[2 * c], b = v[2 * c + 1];
    uint4 o;
    o.x = pack_bf16x2(a.x * inv, a.y * inv);
    o.y = pack_bf16x2(a.z * inv, a.w * inv);
    o.z = pack_bf16x2(b.x * inv, b.y * inv);
    o.w = pack_bf16x2(b.z * inv, b.w * inv);
    ((uint4*)&T[row][0])[(half * 8 + c) ^ (row & 15)] = o;
  }
}

// Persistent-block fused kernel — FINAL (R8 structure + R11 XCD swizzle,
// verified best at 278.2us). Block b owns bn (Bs staged once, resident);
// loops 8 bm-tiles; bm0 = b&7 keeps a bm-group on one XCD for L2 sharing.
// All barriers lgkm-only so tile-t stores stay in flight across
// tile-(t+1) staging + MFMA. Known residual (~17us over the 41us write
// floor): per-wave in-order vmcnt FIFO makes round-t+1 staging loads wait
// behind round-t slab stores; all attempted fixes (nt stores, smaller
// tiles, symmetry, wave specialization, register prefetch x2) regressed —
// removing it needs registers (spills) or waves (LDS-capped) we don't have.
__global__ __launch_bounds__(256, 2) void sim_kernel(const float* __restrict__ z,
                                                     const float* __restrict__ H,
                                                     float* __restrict__ out) {
  __shared__ __align__(16) unsigned char smem_raw[65536];
  unsigned short (*As)[128] = (unsigned short (*)[128])smem_raw;            // 32 KB (aliased by fS slabs)
  unsigned short (*Bs)[128] = (unsigned short (*)[128])(smem_raw + 32768);  // 32 KB persistent
  float* fS = (float*)smem_raw;   // per-wave slabs: wv*2048 + parity*1024 floats

  int tid = threadIdx.x;
  int b = (int)blockIdx.x;
  int bm0 = b & 7;                // XCD id under round-robin dispatch
  int bn = b >> 3;                // 0..63

  int wv = tid >> 6, lane = tid & 63;
  int wm = (wv >> 1) * 64, wn = (wv & 1) * 64;
  int m16 = lane & 15, g = lane >> 4;
  float* fSw = fS + wv * 2048;

  // ---- stage Bs once (resident for all 8 tiles) ----
  stage_tile(z, bn, Bs, tid);

  for (int t = 0; t < 8; ++t) {
    int bm = bm0 * 8 + t;

    // All waves' slab ds_reads from tile t-1 done -> safe to overwrite the
    // As/slab region. Global stores stay in flight.
    lgkm_barrier();
    stage_tile(z, bm, As, tid);
    lgkm_barrier();   // staging visible to all waves

    // ---- MFMA: wave -> 64x64 quadrant, 4x4 tiles of 16x16x32, K=128 ----
    f32x4 acc[4][4] = {};
#pragma unroll
    for (int kc = 0; kc < 4; ++kc) {
      bf16x8 fa[4], fb[4];
      int chunk = kc * 4 + g;
      int cs = (chunk ^ m16) * 8;   // row bases multiples of 16 -> row&15 == m16
#pragma unroll
      for (int tt = 0; tt < 4; ++tt) {
        fa[tt] = *(const bf16x8*)&As[wm + tt * 16 + m16][cs];
        fb[tt] = *(const bf16x8*)&Bs[wn + tt * 16 + m16][cs];
      }
#pragma unroll
      for (int tm = 0; tm < 4; ++tm)
#pragma unroll
        for (int tn = 0; tn < 4; ++tn)
          acc[tm][tn] = __builtin_amdgcn_mfma_f32_16x16x32_bf16(fa[tm], fb[tn], acc[tm][tn], 0, 0, 0);
    }

    lgkm_barrier();   // all waves' As frag reads done before slab writes

    // ---- epilogue + wave-local slab stores (no cross-wave sync needed) ----
    // C/D layout: col=lane&15, row=g*4+r. Slab = 16 rows x 64 cols fp32,
    // swizzle chunk' = (col>>2) ^ rowInSlab.
#pragma unroll
    for (int tm = 0; tm < 4; ++tm) {
      float* slab = fSw + (tm & 1) * 1024;
#pragma unroll
      for (int tn = 0; tn < 4; ++tn) {
        int colq = tn * 16 + m16;          // quadrant-local col 0..63
        int j = bn * 128 + wn + colq;
        f32x4 c = acc[tm][tn];
#pragma unroll
        for (int r = 0; r < 4; ++r) {
          int rs = g * 4 + r;              // slab row 0..15
          int i = bm * 128 + wm + tm * 16 + rs;
          float s = c[r];
          float val = 0.0f;
          if (i == j) {
            val = 1.0f;
          } else if (s > 0.75f) {
            if (lsh_collide(z, H, i, j)) val = s;   // cold path
          }
          slab[rs * 64 + (((colq >> 2) ^ rs) << 2) + (colq & 3)] = val;
        }
      }
      lgkm_fence();   // slab writes complete before cross-lane readback
      // store slab: 4 instrs, each 4 rows x 256B contiguous segments
#pragma unroll
      for (int it = 0; it < 4; ++it) {
        int rs = it * 4 + g;
        f32x4 v = *(const f32x4*)&slab[rs * 64 + ((m16 ^ rs) << 2)];
        int grow = bm * 128 + wm + tm * 16 + rs;
        *(f32x4*)&out[(size_t)grow * N_NODES + bn * 128 + wn + m16 * 4] = v;
      }
    }
  }
}

extern "C" void kernel_launch(void* const* d_in, const int* in_sizes, int n_in,
                              void* d_out, int out_size, void* d_ws, size_t ws_size,
                              hipStream_t stream) {
  const float* z = (const float*)d_in[0];   // [8192, 128] fp32
  const float* H = (const float*)d_in[1];   // [128, 512] fp32
  // d_in[2] = edge_index, unused by the reference forward.
  float* out = (float*)d_out;               // [8192, 8192] fp32
  (void)d_ws; (void)ws_size;

  sim_kernel<<<512, 256, 0, stream>>>(z, H, out);
}